// Round 1
// 474.980 us; speedup vs baseline: 1.0475x; 1.0475x over previous
//
#include <hip/hip_runtime.h>
#include <hip/hip_bf16.h>

#define B_ 32
#define S_ 512
#define H_ 768
#define NH_ 12
#define DH_ 64
#define EC_ 4
#define CAPN_ 8

using short8  = __attribute__((ext_vector_type(8))) short;
using floatx4 = __attribute__((ext_vector_type(4))) float;
using uint2v  = __attribute__((ext_vector_type(2))) unsigned;
using bf16 = __hip_bfloat16;

// async 16B global->LDS. LDS dest must be wave-uniform base + lane*16.
__device__ __forceinline__ void gl_lds16(const void* g, void* l) {
  __builtin_amdgcn_global_load_lds(
      (const __attribute__((address_space(1))) unsigned int*)g,
      (__attribute__((address_space(3))) unsigned int*)l, 16, 0, 0);
}

// pack two f32 -> one u32 of 2 bf16 (lo in low 16 bits)
__device__ __forceinline__ unsigned pk2(float lo, float hi) {
  __hip_bfloat162 h = __float22bfloat162_rn(make_float2(lo, hi));
  unsigned r;
  __builtin_memcpy(&r, &h, 4);
  return r;
}

// ---------- kernel 1: partial sums over S (8 chunks of 64) + fp32->bf16 convert ----------
__global__ void k_mean_convert(const float* __restrict__ X, bf16* __restrict__ Xh,
                               float* __restrict__ partial) {
  int idx = blockIdx.x * 256 + threadIdx.x;          // (b,h) 0..24575
  int b = idx / H_, h = idx - b * H_;
  int s0 = blockIdx.y * 64;
  size_t base = ((size_t)b * S_ + s0) * H_ + h;
  float sum = 0.f;
#pragma unroll 8
  for (int s = 0; s < 64; ++s) {
    float v = X[base + (size_t)s * H_];
    Xh[base + (size_t)s * H_] = __float2bfloat16(v);
    sum += v;
  }
  partial[(size_t)blockIdx.y * (B_ * H_) + idx] = sum;
}

__global__ void k_mean_reduce(const float* __restrict__ partial, float* __restrict__ hmean) {
  int idx = blockIdx.x * 256 + threadIdx.x;
  float s = 0.f;
#pragma unroll
  for (int c = 0; c < 8; ++c) s += partial[(size_t)c * (B_ * H_) + idx];
  hmean[idx] = s * (1.f / 512.f);                    // 1/512 exact
}

// ---------- kernel 2: W[k][n] -> Wt[n][k] bf16, all 4 mats x 8 experts ----------
__global__ void k_wt(const float* __restrict__ Wq, const float* __restrict__ Wk,
                     const float* __restrict__ Wv, const float* __restrict__ Wo,
                     bf16* __restrict__ Wt) {
  __shared__ float tile[32][33];
  int z = blockIdx.z;
  const float* Wbase = (z < 8 ? Wq : z < 16 ? Wk : z < 24 ? Wv : Wo) + (size_t)(z & 7) * H_ * H_;
  int k0 = blockIdx.x * 32, n0 = blockIdx.y * 32;
  int tj = threadIdx.x & 31, ti = threadIdx.x >> 5;  // ti 0..7
#pragma unroll
  for (int r = 0; r < 4; ++r)
    tile[ti + r * 8][tj] = Wbase[(size_t)(k0 + ti + r * 8) * H_ + n0 + tj];
  __syncthreads();
  bf16* out = Wt + (size_t)z * H_ * H_;
#pragma unroll
  for (int r = 0; r < 4; ++r)
    out[(size_t)(n0 + ti + r * 8) * H_ + k0 + tj] = __float2bfloat16(tile[tj][ti + r * 8]);
}

// ---------- routing: gate logits (parallel) + tiny sort ----------
__global__ void k_gate(const float* __restrict__ hmean,
                       const float* __restrict__ Wsc, const float* __restrict__ bsc,
                       const float* __restrict__ Wsu, const float* __restrict__ bsu,
                       float* __restrict__ logits) {
  int b = blockIdx.x;
  int t = threadIdx.x;                               // 64 = 8 gates x 8 partials
  int g = t >> 3, p = t & 7;
  const float* hm = hmean + (size_t)b * H_;
  const float* w;
  float bias;
  if (g < 4) { w = Wsc + g; bias = bsc[g]; }
  else       { w = Wsu + (g - 4); bias = bsu[g - 4]; }
  float acc = 0.f;
  for (int j = p; j < H_; j += 8) acc += hm[j] * w[j * 4];
  acc += __shfl_xor(acc, 1);
  acc += __shfl_xor(acc, 2);
  acc += __shfl_xor(acc, 4);
  if (p == 0) logits[b * 8 + g] = acc + bias;
}

__global__ void k_route2(const float* __restrict__ logits, int* __restrict__ eidx) {
  __shared__ float pcmax[B_];
  __shared__ int rc_s[B_], ru_s[B_];
  int t = threadIdx.x;
  if (t < B_) {
    float lg[8];
#pragma unroll
    for (int e = 0; e < 8; ++e) lg[e] = logits[t * 8 + e];
    float m = lg[0]; int a = 0;                      // first-max ties like jnp.argmax
    for (int e = 1; e < 4; ++e) if (lg[e] > m) { m = lg[e]; a = e; }
    float s = 0.f;
    for (int e = 0; e < 4; ++e) s += expf(lg[e] - m);
    pcmax[t] = 1.f / s;                              // softmax max prob
    rc_s[t] = a;
    float mu = lg[4]; int au = 0;
    for (int e = 1; e < 4; ++e) if (lg[4 + e] > mu) { mu = lg[4 + e]; au = e; }
    ru_s[t] = au;
  }
  __syncthreads();
  if (t == 0) {
    // stable descending selection (equal -> lower index first) == argsort(-p)
    bool used[B_], kept[B_];
    int cnt[EC_] = {0, 0, 0, 0};
    for (int i = 0; i < B_; ++i) used[i] = false;
    for (int i = 0; i < B_; ++i) {
      int best = 0; float bv = -1e30f;
      for (int j = 0; j < B_; ++j)
        if (!used[j] && pcmax[j] > bv) { bv = pcmax[j]; best = j; }
      used[best] = true;
      kept[best] = (++cnt[rc_s[best]] <= CAPN_);
    }
    for (int i = 0; i < B_; ++i)
      eidx[i] = kept[i] ? rc_s[i] : EC_ + ru_s[i];
  }
}

// ---------- GEMM: Y[m][n] = sum_k A[m][k]*Wt[n][k] + bias[n] ----------
// 128x128 tile, BK=64, 256 thr (4 waves of 64x64), XOR-swizzled LDS chunks.
// Double-buffered staging, ONE barrier per K-tile: prefetch(kt+1) issued BEFORE
// compute(kt) so the end-of-iter vmcnt drain is overlapped by the MFMA phase.
// OMODE 0: bf16 out (QKV; bz==2 writes V directly in Vt chunk layout)
// OMODE 1: fp32 out.
template <int OMODE>
__global__ __launch_bounds__(256) void k_gemm(
    const bf16* __restrict__ A, const bf16* __restrict__ Wt,
    const float* __restrict__ bias0, const float* __restrict__ bias1,
    const float* __restrict__ bias2,
    void* out0, void* out1, void* out2,
    const int* __restrict__ eidx, int mat0) {
  __shared__ __align__(16) char lds[2][32768];       // [buf][A 16KB | B 16KB]
  int bz = blockIdx.z;
  int b = blockIdx.y;
  int e = eidx[b];
  int mtile = blockIdx.x & 3, ntile = blockIdx.x >> 2;
  int m0 = mtile * 128, n0 = ntile * 128;
  const bf16* Ab = A + (size_t)b * S_ * H_;
  const bf16* Wb = Wt + (size_t)((mat0 + bz) * 8 + e) * H_ * H_;
  const float* bias = ((bz == 0) ? bias0 : (bz == 1) ? bias1 : bias2) + (size_t)e * H_;
  void* outp = (bz == 0) ? out0 : (bz == 1) ? out1 : out2;

  int t = threadIdx.x, lane = t & 63, w = t >> 6;
  int wm = (w & 1) * 64, wn = (w >> 1) * 64;
  int lm = lane & 15, lq = lane >> 4;

  auto stage = [&](int kt) {
    char* buf = lds[kt & 1];
#pragma unroll
    for (int r = 0; r < 8; ++r) {                    // 2048 chunks of 16B
      int c = t + r * 256;
      const bf16* g;
      if (c < 1024) {
        int mm = c >> 3, pos = c & 7, kc = pos ^ (mm & 7);
        g = Ab + (size_t)(m0 + mm) * H_ + kt * 64 + kc * 8;
      } else {
        int c2 = c - 1024;
        int nn = c2 >> 3, pos = c2 & 7, kc = pos ^ (nn & 7);
        g = Wb + (size_t)(n0 + nn) * H_ + kt * 64 + kc * 8;
      }
      gl_lds16(g, buf + (size_t)c * 16);
    }
  };

  floatx4 acc[4][4] = {};
  stage(0);
  __syncthreads();                                   // prologue: tile 0 ready
  for (int kt = 0; kt < 12; ++kt) {
    if (kt < 11) stage(kt + 1);                      // prefetch into other buffer
    const char* cur = lds[kt & 1];
#pragma unroll
    for (int kf = 0; kf < 2; ++kf) {
      int kc = kf * 4 + lq;
      short8 af[4], bf[4];
#pragma unroll
      for (int mf = 0; mf < 4; ++mf) {
        int mm = wm + mf * 16 + lm;
        af[mf] = *(const short8*)(cur + ((size_t)(mm * 8 + (kc ^ (mm & 7)))) * 16);
      }
#pragma unroll
      for (int nf = 0; nf < 4; ++nf) {
        int nn = wn + nf * 16 + lm;
        bf[nf] = *(const short8*)(cur + 16384 + ((size_t)(nn * 8 + (kc ^ (nn & 7)))) * 16);
      }
#pragma unroll
      for (int mf = 0; mf < 4; ++mf)
#pragma unroll
        for (int nf = 0; nf < 4; ++nf)
          acc[mf][nf] = __builtin_amdgcn_mfma_f32_16x16x32_bf16(af[mf], bf[nf], acc[mf][nf], 0, 0, 0);
    }
    if (kt < 11) __syncthreads();                    // drain prefetch (overlapped) + WAR
  }
  // epilogue: C/D layout col=lane&15, row=quad*4+reg
#pragma unroll
  for (int mf = 0; mf < 4; ++mf) {
#pragma unroll
    for (int nf = 0; nf < 4; ++nf) {
      int n = n0 + wn + nf * 16 + lm;
      float bv = bias[n];
      int mrow = m0 + wm + mf * 16 + lq * 4;
      size_t rowbase = ((size_t)b * S_ + mrow) * H_ + n;
#pragma unroll
      for (int r = 0; r < 4; ++r) {
        float v = acc[mf][nf][r] + bv;
        if (OMODE == 0) {
          if (bz == 2) {
            // V: write directly in Vt chunk layout [b*NH+h][s>>3][dh][s&7]
            int s = mrow + r;
            ((bf16*)outp)[((size_t)(b * NH_ + (n >> 6))) * 32768 +
                          (size_t)(s >> 3) * 512 + (n & 63) * 8 + (s & 7)] =
                __float2bfloat16(v);
          } else {
            ((bf16*)outp)[rowbase + (size_t)r * H_] = __float2bfloat16(v);
          }
        } else {
          ((float*)outp)[rowbase + (size_t)r * H_] = v;
        }
      }
    }
  }
}

// ---------- attention: barrier-free flash, fully in-register softmax ----------
// Block = 4 independent waves x 32 q-rows, one (b,h). Swapped-operand MFMAs:
//   S^T = mfma(K', Q)  with K rows permuted at load so that lane (lq,lm) ends up
//   holding S for q = mf*16+lm, k = {8lq..8lq+3}+4(nf&1)+32(nf>>1) -> the 16 P
//   values each lane needs are exactly its own PV B-frag elements (no LDS, no
//   cross-lane P movement; cvt_pk packs them in-register).
//   O^T = mfma(V^T, P^T): the Vt chunk layout already IS the V^T A-frag, and the
//   O^T accumulator's q-index is lane&15 == softmax state's q-index, so rescale
//   and 1/l need no transpose. Row-reduce = 15 lane-local ops + 2 shfl_xor.
// ds-class ops per wave per K-tile: 8 (was ~68). LDS usage: 0 (was 18.4 KB).
// Grid (B*NH, 4): the 4 q-blocks of one (b,h) differ by 384 ≡ 0 (mod 8) in
// linear wg id -> same XCD -> K/V L2 reuse stays XCD-local.
__global__ __launch_bounds__(256, 3) void k_attn(
    const bf16* __restrict__ Q, const bf16* __restrict__ K,
    const bf16* __restrict__ Vt, const float* __restrict__ mask,
    bf16* __restrict__ Ctx) {
  int bh = blockIdx.x;
  int b = bh / NH_, h = bh - b * NH_;
  int t = threadIdx.x, lane = t & 63, w = t >> 6;
  int lm = lane & 15, lq = lane >> 4;
  int q0 = blockIdx.y * 128 + w * 32;                // this wave's 32 q-rows

  // Q B-frags (col=q=lm, k=kf*32+lq*8+e), one-shot from global
  short8 qf[2][2];
#pragma unroll
  for (int mf = 0; mf < 2; ++mf)
#pragma unroll
    for (int kf = 0; kf < 2; ++kf)
      qf[mf][kf] = *(const short8*)(Q + ((size_t)(b * S_ + q0 + mf * 16 + lm)) * H_ +
                                    h * DH_ + kf * 32 + lq * 8);

  // permuted K row for the A-frag: load row lm holds K row kr + koff[nf]
  int kr = ((lm >> 2) << 3) + (lm & 3);
  const int koff[4] = {0, 4, 32, 36};
  const bf16* kbase = K + ((size_t)(b * S_) + kr) * H_ + h * DH_ + lq * 8;
  const bf16* vtb = Vt + ((size_t)(b * NH_ + h)) * 32768;
  const float* mbase = mask + (size_t)b * S_ + lq * 8;

  floatx4 oacc[2][4] = {};                           // O^T: rows d=nf*16+4lq+r, col q=mf*16+lm
  float m_[2] = {-1e30f, -1e30f}, l_[2] = {0.f, 0.f};

  for (int kt = 0; kt < 8; ++kt) {
    // ---- S^T = K' Q : K A-frags straight from global (permuted rows) ----
    floatx4 sT[2][4] = {};
#pragma unroll
    for (int kf = 0; kf < 2; ++kf) {
      short8 kb4[4];
#pragma unroll
      for (int nf = 0; nf < 4; ++nf)
        kb4[nf] = *(const short8*)(kbase + (size_t)(kt * 64 + koff[nf]) * H_ + kf * 32);
#pragma unroll
      for (int mf = 0; mf < 2; ++mf)
#pragma unroll
        for (int nf = 0; nf < 4; ++nf)
          sT[mf][nf] = __builtin_amdgcn_mfma_f32_16x16x32_bf16(kb4[nf], qf[mf][kf], sT[mf][nf], 0, 0, 0);
    }
    // ---- V^T A-frags (issue early; latency hides under softmax VALU) ----
    short8 vf[2][4];
#pragma unroll
    for (int kf = 0; kf < 2; ++kf)
#pragma unroll
      for (int nf = 0; nf < 4; ++nf)
        vf[kf][nf] = *(const short8*)(vtb + (size_t)(kt * 8 + kf * 4 + lq) * 512 +
                                      (nf * 16 + lm) * 8);
    // ---- mask slots: k_rel = koff[nf] + 8*lq + r ----
    const floatx4* mp = (const floatx4*)(mbase + kt * 64);
    floatx4 mv[4] = {mp[0], mp[1], mp[8], mp[9]};

    // ---- lane-local online softmax (q = mf*16+lm; 16 k-slots per lane) ----
    short8 pf[2][2];
#pragma unroll
    for (int mf = 0; mf < 2; ++mf) {
      float p[4][4];
#pragma unroll
      for (int nf = 0; nf < 4; ++nf)
#pragma unroll
        for (int r = 0; r < 4; ++r)
          p[nf][r] = sT[mf][nf][r] * 0.125f + mv[nf][r];
      float t01 = fmaxf(fmaxf(fmaxf(p[0][0], p[0][1]), fmaxf(p[0][2], p[0][3])),
                        fmaxf(fmaxf(p[1][0], p[1][1]), fmaxf(p[1][2], p[1][3])));
      float t23 = fmaxf(fmaxf(fmaxf(p[2][0], p[2][1]), fmaxf(p[2][2], p[2][3])),
                        fmaxf(fmaxf(p[3][0], p[3][1]), fmaxf(p[3][2], p[3][3])));
      float tm = fmaxf(t01, t23);
      tm = fmaxf(tm, __shfl_xor(tm, 16));
      tm = fmaxf(tm, __shfl_xor(tm, 32));
      float mn = fmaxf(m_[mf], tm);
      float a = __expf(m_[mf] - mn);
      m_[mf] = mn;
      float ps = 0.f;
#pragma unroll
      for (int nf = 0; nf < 4; ++nf)
#pragma unroll
        for (int r = 0; r < 4; ++r) {
          p[nf][r] = __expf(p[nf][r] - mn);
          ps += p[nf][r];
        }
      ps += __shfl_xor(ps, 16);
      ps += __shfl_xor(ps, 32);
      l_[mf] = l_[mf] * a + ps;
#pragma unroll
      for (int nf = 0; nf < 4; ++nf) oacc[mf][nf] *= a;
      union { short8 s8; unsigned u[4]; } pku;
      pku.u[0] = pk2(p[0][0], p[0][1]); pku.u[1] = pk2(p[0][2], p[0][3]);
      pku.u[2] = pk2(p[1][0], p[1][1]); pku.u[3] = pk2(p[1][2], p[1][3]);
      pf[mf][0] = pku.s8;
      pku.u[0] = pk2(p[2][0], p[2][1]); pku.u[1] = pk2(p[2][2], p[2][3]);
      pku.u[2] = pk2(p[3][0], p[3][1]); pku.u[3] = pk2(p[3][2], p[3][3]);
      pf[mf][1] = pku.s8;
    }
    // ---- O^T += V^T P^T ----
#pragma unroll
    for (int kf = 0; kf < 2; ++kf)
#pragma unroll
      for (int mf = 0; mf < 2; ++mf)
#pragma unroll
        for (int nf = 0; nf < 4; ++nf)
          oacc[mf][nf] = __builtin_amdgcn_mfma_f32_16x16x32_bf16(vf[kf][nf], pf[mf][kf], oacc[mf][nf], 0, 0, 0);
  }
  // ---- epilogue: O^T rows d=nf*16+4lq+r, col q=mf*16+lm; 8B vector stores ----
#pragma unroll
  for (int mf = 0; mf < 2; ++mf) {
    float inv = 1.f / l_[mf];
    bf16* op = Ctx + ((size_t)(b * S_ + q0 + mf * 16 + lm)) * H_ + h * DH_ + lq * 4;
#pragma unroll
    for (int nf = 0; nf < 4; ++nf) {
      uint2v o;
      o.x = pk2(oacc[mf][nf][0] * inv, oacc[mf][nf][1] * inv);
      o.y = pk2(oacc[mf][nf][2] * inv, oacc[mf][nf][3] * inv);
      *(uint2v*)(op + nf * 16) = o;
    }
  }
}

extern "C" void kernel_launch(void* const* d_in, const int* in_sizes, int n_in,
                              void* d_out, int out_size, void* d_ws, size_t ws_size,
                              hipStream_t stream) {
  const float* X    = (const float*)d_in[0];
  const float* mask = (const float*)d_in[1];
  const float* Wq   = (const float*)d_in[2];
  const float* bq   = (const float*)d_in[3];
  const float* Wk   = (const float*)d_in[4];
  const float* bk   = (const float*)d_in[5];
  const float* Wv   = (const float*)d_in[6];
  const float* bv   = (const float*)d_in[7];
  const float* Wo   = (const float*)d_in[8];
  const float* bo   = (const float*)d_in[9];
  const float* Wsc  = (const float*)d_in[10];
  const float* bsc  = (const float*)d_in[11];
  const float* Wsu  = (const float*)d_in[12];
  const float* bsu  = (const float*)d_in[13];

  char* ws = (char*)d_ws;
  int*   eidx    = (int*)ws;                        //       128 B @ 0
  float* logits  = (float*)(ws + 128);              //     1,024 B
  float* partial = (float*)(ws + 1280);             //   786,432 B
  float* hmean   = (float*)(ws + 787712);           //    98,304 B
  bf16*  Xh      = (bf16*)(ws + 886016);            // 25,165,824 B
  bf16*  Wt      = (bf16*)(ws + 26051840);          // 37,748,736 B
  bf16*  qb      = (bf16*)(ws + 63800576);          // 25,165,824 B
  bf16*  kb      = (bf16*)(ws + 88966400);          // 25,165,824 B
  bf16*  Vt      = (bf16*)(ws + 114132224);         // 25,165,824 B -> 139,298,048 total
  bf16*  ctx     = Xh;                              // alias: Xh dead after QKV GEMM

  k_mean_convert<<<dim3(96, 8), 256, 0, stream>>>(X, Xh, partial);
  k_mean_reduce<<<96, 256, 0, stream>>>(partial, hmean);
  k_wt<<<dim3(24, 24, 32), 256, 0, stream>>>(Wq, Wk, Wv, Wo, Wt);
  k_gate<<<B_, 64, 0, stream>>>(hmean, Wsc, bsc, Wsu, bsu, logits);
  k_route2<<<1, 64, 0, stream>>>(logits, eidx);
  k_gemm<0><<<dim3(24, 32, 3), 256, 0, stream>>>(Xh, Wt, bq, bk, bv,
                                                 (void*)qb, (void*)kb, (void*)Vt, eidx, 0);
  k_attn<<<dim3(B_ * NH_, 4), 256, 0, stream>>>(qb, kb, Vt, mask, ctx);
  k_gemm<1><<<dim3(24, 32, 1), 256, 0, stream>>>(ctx, Wt, bo, bo, bo,
                                                 d_out, d_out, d_out, eidx, 3);
}

// Round 2
// 467.194 us; speedup vs baseline: 1.0649x; 1.0167x over previous
//
#include <hip/hip_runtime.h>
#include <hip/hip_bf16.h>

#define B_ 32
#define S_ 512
#define H_ 768
#define NH_ 12
#define DH_ 64
#define EC_ 4
#define CAPN_ 8

using short8  = __attribute__((ext_vector_type(8))) short;
using floatx4 = __attribute__((ext_vector_type(4))) float;
using uint2v  = __attribute__((ext_vector_type(2))) unsigned;
using bf16 = __hip_bfloat16;

#define VMCNT(n) asm volatile("s_waitcnt vmcnt(" #n ")" ::: "memory")

// async 16B global->LDS. LDS dest must be wave-uniform base + lane*16.
__device__ __forceinline__ void gl_lds16(const void* g, void* l) {
  __builtin_amdgcn_global_load_lds(
      (const __attribute__((address_space(1))) unsigned int*)g,
      (__attribute__((address_space(3))) unsigned int*)l, 16, 0, 0);
}

// pack two f32 -> one u32 of 2 bf16 (lo in low 16 bits)
__device__ __forceinline__ unsigned pk2(float lo, float hi) {
  __hip_bfloat162 h = __float22bfloat162_rn(make_float2(lo, hi));
  unsigned r;
  __builtin_memcpy(&r, &h, 4);
  return r;
}

// ---------- kernel 1: partial sums over S (8 chunks of 64) + fp32->bf16 convert ----------
__global__ void k_mean_convert(const float* __restrict__ X, bf16* __restrict__ Xh,
                               float* __restrict__ partial) {
  int idx = blockIdx.x * 256 + threadIdx.x;          // (b,h) 0..24575
  int b = idx / H_, h = idx - b * H_;
  int s0 = blockIdx.y * 64;
  size_t base = ((size_t)b * S_ + s0) * H_ + h;
  float sum = 0.f;
#pragma unroll 8
  for (int s = 0; s < 64; ++s) {
    float v = X[base + (size_t)s * H_];
    Xh[base + (size_t)s * H_] = __float2bfloat16(v);
    sum += v;
  }
  partial[(size_t)blockIdx.y * (B_ * H_) + idx] = sum;
}

__global__ void k_mean_reduce(const float* __restrict__ partial, float* __restrict__ hmean) {
  int idx = blockIdx.x * 256 + threadIdx.x;
  float s = 0.f;
#pragma unroll
  for (int c = 0; c < 8; ++c) s += partial[(size_t)c * (B_ * H_) + idx];
  hmean[idx] = s * (1.f / 512.f);                    // 1/512 exact
}

// ---------- kernel 2: W[k][n] -> Wt[n][k] bf16, all 4 mats x 8 experts ----------
__global__ void k_wt(const float* __restrict__ Wq, const float* __restrict__ Wk,
                     const float* __restrict__ Wv, const float* __restrict__ Wo,
                     bf16* __restrict__ Wt) {
  __shared__ float tile[32][33];
  int z = blockIdx.z;
  const float* Wbase = (z < 8 ? Wq : z < 16 ? Wk : z < 24 ? Wv : Wo) + (size_t)(z & 7) * H_ * H_;
  int k0 = blockIdx.x * 32, n0 = blockIdx.y * 32;
  int tj = threadIdx.x & 31, ti = threadIdx.x >> 5;  // ti 0..7
#pragma unroll
  for (int r = 0; r < 4; ++r)
    tile[ti + r * 8][tj] = Wbase[(size_t)(k0 + ti + r * 8) * H_ + n0 + tj];
  __syncthreads();
  bf16* out = Wt + (size_t)z * H_ * H_;
#pragma unroll
  for (int r = 0; r < 4; ++r)
    out[(size_t)(n0 + ti + r * 8) * H_ + k0 + tj] = __float2bfloat16(tile[tj][ti + r * 8]);
}

// ---------- routing: gate logits (parallel) + tiny sort ----------
__global__ void k_gate(const float* __restrict__ hmean,
                       const float* __restrict__ Wsc, const float* __restrict__ bsc,
                       const float* __restrict__ Wsu, const float* __restrict__ bsu,
                       float* __restrict__ logits) {
  int b = blockIdx.x;
  int t = threadIdx.x;                               // 64 = 8 gates x 8 partials
  int g = t >> 3, p = t & 7;
  const float* hm = hmean + (size_t)b * H_;
  const float* w;
  float bias;
  if (g < 4) { w = Wsc + g; bias = bsc[g]; }
  else       { w = Wsu + (g - 4); bias = bsu[g - 4]; }
  float acc = 0.f;
  for (int j = p; j < H_; j += 8) acc += hm[j] * w[j * 4];
  acc += __shfl_xor(acc, 1);
  acc += __shfl_xor(acc, 2);
  acc += __shfl_xor(acc, 4);
  if (p == 0) logits[b * 8 + g] = acc + bias;
}

__global__ void k_route2(const float* __restrict__ logits, int* __restrict__ eidx) {
  __shared__ float pcmax[B_];
  __shared__ int rc_s[B_], ru_s[B_];
  int t = threadIdx.x;
  if (t < B_) {
    float lg[8];
#pragma unroll
    for (int e = 0; e < 8; ++e) lg[e] = logits[t * 8 + e];
    float m = lg[0]; int a = 0;                      // first-max ties like jnp.argmax
    for (int e = 1; e < 4; ++e) if (lg[e] > m) { m = lg[e]; a = e; }
    float s = 0.f;
    for (int e = 0; e < 4; ++e) s += expf(lg[e] - m);
    pcmax[t] = 1.f / s;                              // softmax max prob
    rc_s[t] = a;
    float mu = lg[4]; int au = 0;
    for (int e = 1; e < 4; ++e) if (lg[4 + e] > mu) { mu = lg[4 + e]; au = e; }
    ru_s[t] = au;
  }
  __syncthreads();
  if (t == 0) {
    // stable descending selection (equal -> lower index first) == argsort(-p)
    bool used[B_], kept[B_];
    int cnt[EC_] = {0, 0, 0, 0};
    for (int i = 0; i < B_; ++i) used[i] = false;
    for (int i = 0; i < B_; ++i) {
      int best = 0; float bv = -1e30f;
      for (int j = 0; j < B_; ++j)
        if (!used[j] && pcmax[j] > bv) { bv = pcmax[j]; best = j; }
      used[best] = true;
      kept[best] = (++cnt[rc_s[best]] <= CAPN_);
    }
    for (int i = 0; i < B_; ++i)
      eidx[i] = kept[i] ? rc_s[i] : EC_ + ru_s[i];
  }
}

// ---------- GEMM: 256x256 tile, BK=64, 8 waves (2Mx4N), 8-phase counted-vmcnt ----------
// Y[m][n] = sum_k A[m][k]*Wt[n][k] + bias[n].  K=768 -> 12 K-tiles.
// LDS 2 x 64KB buffers (A 32KB | B 32KB), chunk-XOR swizzle (proven 0-conflict).
// Staging at half-tile ("pair") granularity, aligned with quadrant consumption:
//   pair0 = A rows {0-63,128-191}   (consumed by quadrant mh=0)
//   pair1 = A rows {64-127,192-255} (mh=1)
//   pair2 = B even 32-row slices    (nh=0)
//   pair3 = B odd  32-row slices    (nh=1)
// Per K-tile: 4 phases {stage 1 pair (2 loads) -> vmcnt(6) -> s_barrier ->
// ds_read frags -> setprio(1) 16xMFMA setprio(0)}; issue order pair 0,2,3,1 so
// each pair has >=3 phases to land before its consuming phase next tile.
// vmcnt never 0 in the main loop; last tile drains 4->2->0.
// OMODE 0: bf16 out (QKV; mat==2 writes V directly in Vt chunk layout)
// OMODE 1: fp32 out.
template <int OMODE>
__global__ __launch_bounds__(512, 2) void k_gemm(
    const bf16* __restrict__ A, const bf16* __restrict__ Wt,
    const float* __restrict__ bias0, const float* __restrict__ bias1,
    const float* __restrict__ bias2,
    void* out0, void* out1, void* out2,
    const int* __restrict__ eidx, int mat0, int nm) {
  __shared__ __align__(16) char lds[2][65536];       // [buf][A 32KB | B 32KB]
  // XCD-chunked bijective decode: consecutive f on one XCD -> one batch's
  // blocks (which share the 768KB A panel) stay XCD-local.
  int nwg = gridDim.x;                               // 576 (QKV) or 192 (O) - %8==0
  int wg = blockIdx.x;
  int f = (wg & 7) * (nwg >> 3) + (wg >> 3);
  int b = f / (6 * nm);
  int r0 = f - b * 6 * nm;
  int mat = r0 / 6;
  int tile = r0 - mat * 6;
  int m0 = (tile & 1) * 256, n0 = (tile >> 1) * 256;
  int e = eidx[b];
  const bf16* Ab = A + (size_t)b * S_ * H_;
  const bf16* Wb = Wt + (size_t)((mat0 + mat) * 8 + e) * H_ * H_;
  const float* bias = ((mat == 0) ? bias0 : (mat == 1) ? bias1 : bias2) + (size_t)e * H_;
  void* outp = (mat == 0) ? out0 : (mat == 1) ? out1 : out2;

  int t = threadIdx.x, lane = t & 63, w = t >> 6;
  int wm = w >> 2, wn = w & 3;                       // 2M x 4N waves, 128x64 each
  int lm = lane & 15, lq = lane >> 4;

  auto stage_pair = [&](int p, int kt) {             // p literal at call sites
    char* buf = lds[kt & 1];
#pragma unroll
    for (int s = 0; s < 2; ++s) {
      int idx = t + s * 512;                         // 0..1023 chunk-in-pair
      int row, isB;
      if (p == 0)      { row = (idx >> 9) * 128 +      ((idx & 511) >> 3); isB = 0; }
      else if (p == 1) { row = (idx >> 9) * 128 + 64 + ((idx & 511) >> 3); isB = 0; }
      else if (p == 2) { row = (idx >> 8) * 64 +       ((idx & 255) >> 3); isB = 1; }
      else             { row = (idx >> 8) * 64 + 32 +  ((idx & 255) >> 3); isB = 1; }
      int pos = idx & 7;
      int kc = pos ^ (row & 7);                      // chunk-XOR swizzle
      const bf16* g = (isB ? Wb + (size_t)(n0 + row) * H_
                           : Ab + (size_t)(m0 + row) * H_) + kt * 64 + kc * 8;
      gl_lds16(g, buf + isB * 32768 + row * 128 + pos * 16);
    }
  };

  short8 af[4][2], bf0[2][2], bf1[2][2];
  auto ldA = [&](const char* cur, int mh) {
#pragma unroll
    for (int mf = 0; mf < 4; ++mf) {
      int mm = wm * 128 + mh * 64 + mf * 16 + lm;
#pragma unroll
      for (int kf = 0; kf < 2; ++kf) {
        int kc = kf * 4 + lq;
        af[mf][kf] = *(const short8*)(cur + ((size_t)(mm * 8 + (kc ^ (mm & 7)))) * 16);
      }
    }
  };
  auto ldB = [&](const char* cur, int nh, short8 bfr[2][2]) {
#pragma unroll
    for (int nf = 0; nf < 2; ++nf) {
      int nn = wn * 64 + nh * 32 + nf * 16 + lm;
#pragma unroll
      for (int kf = 0; kf < 2; ++kf) {
        int kc = kf * 4 + lq;
        bfr[nf][kf] = *(const short8*)(cur + 32768 + ((size_t)(nn * 8 + (kc ^ (nn & 7)))) * 16);
      }
    }
  };

  floatx4 acc[8][4] = {};
  auto mfma16 = [&](short8 bfr[2][2], int mh, int nh) {
    __builtin_amdgcn_s_setprio(1);
#pragma unroll
    for (int kf = 0; kf < 2; ++kf)
#pragma unroll
      for (int mf = 0; mf < 4; ++mf)
#pragma unroll
        for (int nf = 0; nf < 2; ++nf)
          acc[mh * 4 + mf][nh * 2 + nf] = __builtin_amdgcn_mfma_f32_16x16x32_bf16(
              af[mf][kf], bfr[nf][kf], acc[mh * 4 + mf][nh * 2 + nf], 0, 0, 0);
    __builtin_amdgcn_s_setprio(0);
  };

  // prologue: tile 0
  stage_pair(0, 0); stage_pair(2, 0); stage_pair(3, 0); stage_pair(1, 0);
  VMCNT(0);
  __builtin_amdgcn_s_barrier();
  __builtin_amdgcn_sched_barrier(0);

  for (int j = 0; j < 11; ++j) {
    const char* cur = lds[j & 1];
    // phase A (mh0,nh0)
    stage_pair(0, j + 1);
    VMCNT(6); __builtin_amdgcn_s_barrier(); __builtin_amdgcn_sched_barrier(0);
    ldB(cur, 0, bf0); ldA(cur, 0);
    mfma16(bf0, 0, 0);
    // phase B (mh0,nh1)
    stage_pair(2, j + 1);
    VMCNT(6); __builtin_amdgcn_s_barrier(); __builtin_amdgcn_sched_barrier(0);
    ldB(cur, 1, bf1);
    mfma16(bf1, 0, 1);
    // phase C (mh1,nh1)
    stage_pair(3, j + 1);
    VMCNT(6); __builtin_amdgcn_s_barrier(); __builtin_amdgcn_sched_barrier(0);
    ldA(cur, 1);
    mfma16(bf1, 1, 1);
    // phase D (mh1,nh0) - operands already in regs; end-of-tile barrier = WAR
    stage_pair(1, j + 1);
    mfma16(bf0, 1, 0);
    __builtin_amdgcn_s_barrier(); __builtin_amdgcn_sched_barrier(0);
  }
  { // tile 11 peeled: no staging, drain 4 -> 2 -> 0
    const char* cur = lds[1];
    VMCNT(4); __builtin_amdgcn_s_barrier(); __builtin_amdgcn_sched_barrier(0);
    ldB(cur, 0, bf0); ldA(cur, 0);
    mfma16(bf0, 0, 0);
    VMCNT(2); __builtin_amdgcn_s_barrier(); __builtin_amdgcn_sched_barrier(0);
    ldB(cur, 1, bf1);
    mfma16(bf1, 0, 1);
    VMCNT(0); __builtin_amdgcn_s_barrier(); __builtin_amdgcn_sched_barrier(0);
    ldA(cur, 1);
    mfma16(bf1, 1, 1);
    mfma16(bf0, 1, 0);
  }

  // epilogue: C/D layout col=lane&15, row=quad*4+reg
#pragma unroll
  for (int mi = 0; mi < 8; ++mi) {
#pragma unroll
    for (int ni = 0; ni < 4; ++ni) {
      int n = n0 + wn * 64 + ni * 16 + lm;
      float bvv = bias[n];
      int mrow = m0 + wm * 128 + mi * 16 + lq * 4;
      size_t rowbase = ((size_t)b * S_ + mrow) * H_ + n;
#pragma unroll
      for (int r = 0; r < 4; ++r) {
        float v = acc[mi][ni][r] + bvv;
        if (OMODE == 0) {
          if (mat == 2) {
            // V: write directly in Vt chunk layout [b*NH+h][s>>3][dh][s&7]
            int s = mrow + r;
            ((bf16*)outp)[((size_t)(b * NH_ + (n >> 6))) * 32768 +
                          (size_t)(s >> 3) * 512 + (n & 63) * 8 + (s & 7)] =
                __float2bfloat16(v);
          } else {
            ((bf16*)outp)[rowbase + (size_t)r * H_] = __float2bfloat16(v);
          }
        } else {
          ((float*)outp)[rowbase + (size_t)r * H_] = v;
        }
      }
    }
  }
}

// ---------- attention: barrier-free flash, fully in-register softmax ----------
// Block = 4 independent waves x 32 q-rows, one (b,h). Swapped-operand MFMAs:
//   S^T = mfma(K', Q)  with K rows permuted at load so that lane (lq,lm) ends up
//   holding S for q = mf*16+lm, k = {8lq..8lq+3}+4(nf&1)+32(nf>>1) -> the 16 P
//   values each lane needs are exactly its own PV B-frag elements (no LDS, no
//   cross-lane P movement; cvt_pk packs them in-register).
//   O^T = mfma(V^T, P^T): the Vt chunk layout already IS the V^T A-frag, and the
//   O^T accumulator's q-index is lane&15 == softmax state's q-index, so rescale
//   and 1/l need no transpose. Row-reduce = 15 lane-local ops + 2 shfl_xor.
__global__ __launch_bounds__(256, 3) void k_attn(
    const bf16* __restrict__ Q, const bf16* __restrict__ K,
    const bf16* __restrict__ Vt, const float* __restrict__ mask,
    bf16* __restrict__ Ctx) {
  int bh = blockIdx.x;
  int b = bh / NH_, h = bh - b * NH_;
  int t = threadIdx.x, lane = t & 63, w = t >> 6;
  int lm = lane & 15, lq = lane >> 4;
  int q0 = blockIdx.y * 128 + w * 32;                // this wave's 32 q-rows

  // Q B-frags (col=q=lm, k=kf*32+lq*8+e), one-shot from global
  short8 qf[2][2];
#pragma unroll
  for (int mf = 0; mf < 2; ++mf)
#pragma unroll
    for (int kf = 0; kf < 2; ++kf)
      qf[mf][kf] = *(const short8*)(Q + ((size_t)(b * S_ + q0 + mf * 16 + lm)) * H_ +
                                    h * DH_ + kf * 32 + lq * 8);

  // permuted K row for the A-frag: load row lm holds K row kr + koff[nf]
  int kr = ((lm >> 2) << 3) + (lm & 3);
  const int koff[4] = {0, 4, 32, 36};
  const bf16* kbase = K + ((size_t)(b * S_) + kr) * H_ + h * DH_ + lq * 8;
  const bf16* vtb = Vt + ((size_t)(b * NH_ + h)) * 32768;
  const float* mbase = mask + (size_t)b * S_ + lq * 8;

  floatx4 oacc[2][4] = {};                           // O^T: rows d=nf*16+4lq+r, col q=mf*16+lm
  float m_[2] = {-1e30f, -1e30f}, l_[2] = {0.f, 0.f};

  for (int kt = 0; kt < 8; ++kt) {
    // ---- S^T = K' Q : K A-frags straight from global (permuted rows) ----
    floatx4 sT[2][4] = {};
#pragma unroll
    for (int kf = 0; kf < 2; ++kf) {
      short8 kb4[4];
#pragma unroll
      for (int nf = 0; nf < 4; ++nf)
        kb4[nf] = *(const short8*)(kbase + (size_t)(kt * 64 + koff[nf]) * H_ + kf * 32);
#pragma unroll
      for (int mf = 0; mf < 2; ++mf)
#pragma unroll
        for (int nf = 0; nf < 4; ++nf)
          sT[mf][nf] = __builtin_amdgcn_mfma_f32_16x16x32_bf16(kb4[nf], qf[mf][kf], sT[mf][nf], 0, 0, 0);
    }
    // ---- V^T A-frags (issue early; latency hides under softmax VALU) ----
    short8 vf[2][4];
#pragma unroll
    for (int kf = 0; kf < 2; ++kf)
#pragma unroll
      for (int nf = 0; nf < 4; ++nf)
        vf[kf][nf] = *(const short8*)(vtb + (size_t)(kt * 8 + kf * 4 + lq) * 512 +
                                      (nf * 16 + lm) * 8);
    // ---- mask slots: k_rel = koff[nf] + 8*lq + r ----
    const floatx4* mp = (const floatx4*)(mbase + kt * 64);
    floatx4 mv[4] = {mp[0], mp[1], mp[8], mp[9]};

    // ---- lane-local online softmax (q = mf*16+lm; 16 k-slots per lane) ----
    short8 pf[2][2];
#pragma unroll
    for (int mf = 0; mf < 2; ++mf) {
      float p[4][4];
#pragma unroll
      for (int nf = 0; nf < 4; ++nf)
#pragma unroll
        for (int r = 0; r < 4; ++r)
          p[nf][r] = sT[mf][nf][r] * 0.125f + mv[nf][r];
      float t01 = fmaxf(fmaxf(fmaxf(p[0][0], p[0][1]), fmaxf(p[0][2], p[0][3])),
                        fmaxf(fmaxf(p[1][0], p[1][1]), fmaxf(p[1][2], p[1][3])));
      float t23 = fmaxf(fmaxf(fmaxf(p[2][0], p[2][1]), fmaxf(p[2][2], p[2][3])),
                        fmaxf(fmaxf(p[3][0], p[3][1]), fmaxf(p[3][2], p[3][3])));
      float tm = fmaxf(t01, t23);
      tm = fmaxf(tm, __shfl_xor(tm, 16));
      tm = fmaxf(tm, __shfl_xor(tm, 32));
      float mn = fmaxf(m_[mf], tm);
      float a = __expf(m_[mf] - mn);
      m_[mf] = mn;
      float ps = 0.f;
#pragma unroll
      for (int nf = 0; nf < 4; ++nf)
#pragma unroll
        for (int r = 0; r < 4; ++r) {
          p[nf][r] = __expf(p[nf][r] - mn);
          ps += p[nf][r];
        }
      ps += __shfl_xor(ps, 16);
      ps += __shfl_xor(ps, 32);
      l_[mf] = l_[mf] * a + ps;
#pragma unroll
      for (int nf = 0; nf < 4; ++nf) oacc[mf][nf] *= a;
      union { short8 s8; unsigned u[4]; } pku;
      pku.u[0] = pk2(p[0][0], p[0][1]); pku.u[1] = pk2(p[0][2], p[0][3]);
      pku.u[2] = pk2(p[1][0], p[1][1]); pku.u[3] = pk2(p[1][2], p[1][3]);
      pf[mf][0] = pku.s8;
      pku.u[0] = pk2(p[2][0], p[2][1]); pku.u[1] = pk2(p[2][2], p[2][3]);
      pku.u[2] = pk2(p[3][0], p[3][1]); pku.u[3] = pk2(p[3][2], p[3][3]);
      pf[mf][1] = pku.s8;
    }
    // ---- O^T += V^T P^T ----
#pragma unroll
    for (int kf = 0; kf < 2; ++kf)
#pragma unroll
      for (int mf = 0; mf < 2; ++mf)
#pragma unroll
        for (int nf = 0; nf < 4; ++nf)
          oacc[mf][nf] = __builtin_amdgcn_mfma_f32_16x16x32_bf16(vf[kf][nf], pf[mf][kf], oacc[mf][nf], 0, 0, 0);
  }
  // ---- epilogue: O^T rows d=nf*16+4lq+r, col q=mf*16+lm; 8B vector stores ----
#pragma unroll
  for (int mf = 0; mf < 2; ++mf) {
    float inv = 1.f / l_[mf];
    bf16* op = Ctx + ((size_t)(b * S_ + q0 + mf * 16 + lm)) * H_ + h * DH_ + lq * 4;
#pragma unroll
    for (int nf = 0; nf < 4; ++nf) {
      uint2v o;
      o.x = pk2(oacc[mf][nf][0] * inv, oacc[mf][nf][1] * inv);
      o.y = pk2(oacc[mf][nf][2] * inv, oacc[mf][nf][3] * inv);
      *(uint2v*)(op + nf * 16) = o;
    }
  }
}

extern "C" void kernel_launch(void* const* d_in, const int* in_sizes, int n_in,
                              void* d_out, int out_size, void* d_ws, size_t ws_size,
                              hipStream_t stream) {
  const float* X    = (const float*)d_in[0];
  const float* mask = (const float*)d_in[1];
  const float* Wq   = (const float*)d_in[2];
  const float* bq   = (const float*)d_in[3];
  const float* Wk   = (const float*)d_in[4];
  const float* bk   = (const float*)d_in[5];
  const float* Wv   = (const float*)d_in[6];
  const float* bv   = (const float*)d_in[7];
  const float* Wo   = (const float*)d_in[8];
  const float* bo   = (const float*)d_in[9];
  const float* Wsc  = (const float*)d_in[10];
  const float* bsc  = (const float*)d_in[11];
  const float* Wsu  = (const float*)d_in[12];
  const float* bsu  = (const float*)d_in[13];

  char* ws = (char*)d_ws;
  int*   eidx    = (int*)ws;                        //       128 B @ 0
  float* logits  = (float*)(ws + 128);              //     1,024 B
  float* partial = (float*)(ws + 1280);             //   786,432 B
  float* hmean   = (float*)(ws + 787712);           //    98,304 B
  bf16*  Xh      = (bf16*)(ws + 886016);            // 25,165,824 B
  bf16*  Wt      = (bf16*)(ws + 26051840);          // 37,748,736 B
  bf16*  qb      = (bf16*)(ws + 63800576);          // 25,165,824 B
  bf16*  kb      = (bf16*)(ws + 88966400);          // 25,165,824 B
  bf16*  Vt      = (bf16*)(ws + 114132224);         // 25,165,824 B -> 139,298,048 total
  bf16*  ctx     = Xh;                              // alias: Xh dead after QKV GEMM

  k_mean_convert<<<dim3(96, 8), 256, 0, stream>>>(X, Xh, partial);
  k_mean_reduce<<<96, 256, 0, stream>>>(partial, hmean);
  k_wt<<<dim3(24, 24, 32), 256, 0, stream>>>(Wq, Wk, Wv, Wo, Wt);
  k_gate<<<B_, 64, 0, stream>>>(hmean, Wsc, bsc, Wsu, bsu, logits);
  k_route2<<<1, 64, 0, stream>>>(logits, eidx);
  // QKV: 2 mtiles x 3 ntiles x 32 b x 3 mats = 576 blocks (1D, XCD-decoded in-kernel)
  k_gemm<0><<<dim3(576), 512, 0, stream>>>(Xh, Wt, bq, bk, bv,
                                           (void*)qb, (void*)kb, (void*)Vt, eidx, 0, 3);
  k_attn<<<dim3(B_ * NH_, 4), 256, 0, stream>>>(qb, kb, Vt, mask, ctx);
  k_gemm<1><<<dim3(192), 512, 0, stream>>>(ctx, Wt, bo, bo, bo,
                                           d_out, d_out, d_out, eidx, 3, 1);
}

// Round 3
// 454.196 us; speedup vs baseline: 1.0954x; 1.0286x over previous
//
#include <hip/hip_runtime.h>
#include <hip/hip_bf16.h>

#define B_ 32
#define S_ 512
#define H_ 768
#define NH_ 12
#define DH_ 64
#define EC_ 4
#define CAPN_ 8

using short8  = __attribute__((ext_vector_type(8))) short;
using floatx4 = __attribute__((ext_vector_type(4))) float;
using uint2v  = __attribute__((ext_vector_type(2))) unsigned;
using bf16 = __hip_bfloat16;

#define VMCNT(n) asm volatile("s_waitcnt vmcnt(" #n ")" ::: "memory")

// async 16B global->LDS. LDS dest must be wave-uniform base + lane*16.
__device__ __forceinline__ void gl_lds16(const void* g, void* l) {
  __builtin_amdgcn_global_load_lds(
      (const __attribute__((address_space(1))) unsigned int*)g,
      (__attribute__((address_space(3))) unsigned int*)l, 16, 0, 0);
}

// pack two f32 -> one u32 of 2 bf16 (lo in low 16 bits)
__device__ __forceinline__ unsigned pk2(float lo, float hi) {
  __hip_bfloat162 h = __float22bfloat162_rn(make_float2(lo, hi));
  unsigned r;
  __builtin_memcpy(&r, &h, 4);
  return r;
}

// ---------- kernel 1: partial sums over S (8 chunks of 64) + fp32->bf16 convert ----------
__global__ void k_mean_convert(const float* __restrict__ X, bf16* __restrict__ Xh,
                               float* __restrict__ partial) {
  int idx = blockIdx.x * 256 + threadIdx.x;          // (b,h) 0..24575
  int b = idx / H_, h = idx - b * H_;
  int s0 = blockIdx.y * 64;
  size_t base = ((size_t)b * S_ + s0) * H_ + h;
  float sum = 0.f;
#pragma unroll 8
  for (int s = 0; s < 64; ++s) {
    float v = X[base + (size_t)s * H_];
    Xh[base + (size_t)s * H_] = __float2bfloat16(v);
    sum += v;
  }
  partial[(size_t)blockIdx.y * (B_ * H_) + idx] = sum;
}

__global__ void k_mean_reduce(const float* __restrict__ partial, float* __restrict__ hmean) {
  int idx = blockIdx.x * 256 + threadIdx.x;
  float s = 0.f;
#pragma unroll
  for (int c = 0; c < 8; ++c) s += partial[(size_t)c * (B_ * H_) + idx];
  hmean[idx] = s * (1.f / 512.f);                    // 1/512 exact
}

// ---------- kernel 2: W[k][n] -> Wt[n][k] bf16, all 4 mats x 8 experts ----------
__global__ void k_wt(const float* __restrict__ Wq, const float* __restrict__ Wk,
                     const float* __restrict__ Wv, const float* __restrict__ Wo,
                     bf16* __restrict__ Wt) {
  __shared__ float tile[32][33];
  int z = blockIdx.z;
  const float* Wbase = (z < 8 ? Wq : z < 16 ? Wk : z < 24 ? Wv : Wo) + (size_t)(z & 7) * H_ * H_;
  int k0 = blockIdx.x * 32, n0 = blockIdx.y * 32;
  int tj = threadIdx.x & 31, ti = threadIdx.x >> 5;  // ti 0..7
#pragma unroll
  for (int r = 0; r < 4; ++r)
    tile[ti + r * 8][tj] = Wbase[(size_t)(k0 + ti + r * 8) * H_ + n0 + tj];
  __syncthreads();
  bf16* out = Wt + (size_t)z * H_ * H_;
#pragma unroll
  for (int r = 0; r < 4; ++r)
    out[(size_t)(n0 + ti + r * 8) * H_ + k0 + tj] = __float2bfloat16(tile[tj][ti + r * 8]);
}

// ---------- routing: gate logits (parallel) + tiny sort ----------
__global__ void k_gate(const float* __restrict__ hmean,
                       const float* __restrict__ Wsc, const float* __restrict__ bsc,
                       const float* __restrict__ Wsu, const float* __restrict__ bsu,
                       float* __restrict__ logits) {
  int b = blockIdx.x;
  int t = threadIdx.x;                               // 64 = 8 gates x 8 partials
  int g = t >> 3, p = t & 7;
  const float* hm = hmean + (size_t)b * H_;
  const float* w;
  float bias;
  if (g < 4) { w = Wsc + g; bias = bsc[g]; }
  else       { w = Wsu + (g - 4); bias = bsu[g - 4]; }
  float acc = 0.f;
  for (int j = p; j < H_; j += 8) acc += hm[j] * w[j * 4];
  acc += __shfl_xor(acc, 1);
  acc += __shfl_xor(acc, 2);
  acc += __shfl_xor(acc, 4);
  if (p == 0) logits[b * 8 + g] = acc + bias;
}

__global__ void k_route2(const float* __restrict__ logits, int* __restrict__ eidx) {
  __shared__ float pcmax[B_];
  __shared__ int rc_s[B_], ru_s[B_];
  int t = threadIdx.x;
  if (t < B_) {
    float lg[8];
#pragma unroll
    for (int e = 0; e < 8; ++e) lg[e] = logits[t * 8 + e];
    float m = lg[0]; int a = 0;                      // first-max ties like jnp.argmax
    for (int e = 1; e < 4; ++e) if (lg[e] > m) { m = lg[e]; a = e; }
    float s = 0.f;
    for (int e = 0; e < 4; ++e) s += expf(lg[e] - m);
    pcmax[t] = 1.f / s;                              // softmax max prob
    rc_s[t] = a;
    float mu = lg[4]; int au = 0;
    for (int e = 1; e < 4; ++e) if (lg[4 + e] > mu) { mu = lg[4 + e]; au = e; }
    ru_s[t] = au;
  }
  __syncthreads();
  if (t == 0) {
    // stable descending selection (equal -> lower index first) == argsort(-p)
    bool used[B_], kept[B_];
    int cnt[EC_] = {0, 0, 0, 0};
    for (int i = 0; i < B_; ++i) used[i] = false;
    for (int i = 0; i < B_; ++i) {
      int best = 0; float bv = -1e30f;
      for (int j = 0; j < B_; ++j)
        if (!used[j] && pcmax[j] > bv) { bv = pcmax[j]; best = j; }
      used[best] = true;
      kept[best] = (++cnt[rc_s[best]] <= CAPN_);
    }
    for (int i = 0; i < B_; ++i)
      eidx[i] = kept[i] ? rc_s[i] : EC_ + ru_s[i];
  }
}

// ---------- GEMM: 128x128 tile, BK=32, 4 waves, TRIPLE-buffered counted-vmcnt ----------
// Y[m][n] = sum_k A[m][k]*Wt[n][k] + bias[n].  K=768 -> 24 K-tiles of 32.
// Grid balance is exact: QKV 2304 blocks = 9x256 CUs, O-proj 768 = 3x256.
// LDS 3 x 16KB buffers (A 8KB | B 8KB) -> 48KB/block -> 3 blocks/CU resident.
// Pipeline: stage(kt+2) issued each iter; end-of-iter s_waitcnt vmcnt(4) retires
// exactly tile kt+1's 4 loads (2-tile prefetch depth, never drains to 0 in the
// main loop), then raw s_barrier (no implicit full drain).
// Chunk-XOR swizzle kc = pos ^ (row&3): all 32 banks hit exactly 8x per
// ds_read_b128 wave-read (even minimum) and gl_lds16 dest stays linear.
// 1D grid, XCD-chunked bijective decode: consecutive f share A panel + W panel.
// OMODE 0: bf16 out (QKV; mat==2 writes V directly in Vt chunk layout)
// OMODE 1: fp32 out.  NM = mats per launch (3 QKV, 1 O) - compile-time.
template <int OMODE, int NM>
__global__ __launch_bounds__(256, 3) void k_gemm(
    const bf16* __restrict__ A, const bf16* __restrict__ Wt,
    const float* __restrict__ bias0, const float* __restrict__ bias1,
    const float* __restrict__ bias2,
    void* out0, void* out1, void* out2,
    const int* __restrict__ eidx, int mat0) {
  __shared__ __align__(16) char lds[3][16384];       // [buf][A 8KB | B 8KB]
  const int nwg = 96 * NM * 8;                       // 2304 or 768 (QKV / O)
  int wg = blockIdx.x;
  int f = (wg & 7) * (nwg >> 3) + (wg >> 3);         // XCD-chunked, bijective
  int b = f / (24 * NM);
  int r0 = f - b * 24 * NM;
  int mat = r0 / 24;
  int tile = r0 - mat * 24;
  int m0 = (tile & 3) * 128, n0 = (tile >> 2) * 128;
  int e = eidx[b];
  const bf16* Ab = A + (size_t)b * S_ * H_;
  const bf16* Wb = Wt + (size_t)((mat0 + mat) * 8 + e) * H_ * H_;
  const float* bias = ((mat == 0) ? bias0 : (mat == 1) ? bias1 : bias2) + (size_t)e * H_;
  void* outp = (mat == 0) ? out0 : (mat == 1) ? out1 : out2;

  int t = threadIdx.x, lane = t & 63, w = t >> 6;
  int wm = (w & 1) * 64, wn = (w >> 1) * 64;
  int lm = lane & 15, lq = lane >> 4;

  auto stage = [&](char* buf, int kt) {
#pragma unroll
    for (int r = 0; r < 4; ++r) {                    // 1024 chunks of 16B
      int c = t + r * 256;
      int isB = c >> 9;
      int cc = c & 511;
      int row = cc >> 2, pos = cc & 3;
      int kc = pos ^ (row & 3);                      // chunk-XOR swizzle
      const bf16* g = (isB ? Wb + (size_t)(n0 + row) * H_
                           : Ab + (size_t)(m0 + row) * H_) + kt * 32 + kc * 8;
      gl_lds16(g, buf + (size_t)c * 16);             // linear dest = base+lane*16
    }
  };

  floatx4 acc[4][4] = {};
  // prologue: tiles 0 and 1 in flight
  stage(lds[0], 0);
  stage(lds[1], 1);
  VMCNT(4);                                          // tile 0 landed
  __builtin_amdgcn_s_barrier();
  __builtin_amdgcn_sched_barrier(0);

  int cb = 0;                                        // buffer holding tile kt
  for (int kt = 0; kt < 24; ++kt) {
    if (kt < 22) {
      int pb = cb + 2; if (pb >= 3) pb -= 3;
      stage(lds[pb], kt + 2);                        // prefetch depth 2
    }
    const char* cur = lds[cb];
    short8 af[4], bfr[4];
#pragma unroll
    for (int mf = 0; mf < 4; ++mf) {
      int mm = wm + mf * 16 + lm;
      af[mf] = *(const short8*)(cur + mm * 64 + ((lq ^ (mm & 3)) * 16));
    }
#pragma unroll
    for (int nf = 0; nf < 4; ++nf) {
      int nn = wn + nf * 16 + lm;
      bfr[nf] = *(const short8*)(cur + 8192 + nn * 64 + ((lq ^ (nn & 3)) * 16));
    }
#pragma unroll
    for (int mf = 0; mf < 4; ++mf)
#pragma unroll
      for (int nf = 0; nf < 4; ++nf)
        acc[mf][nf] = __builtin_amdgcn_mfma_f32_16x16x32_bf16(af[mf], bfr[nf], acc[mf][nf], 0, 0, 0);
    if (kt < 23) {                                   // make tile kt+1 ready; WAR fence
      if (kt < 22) { VMCNT(4); } else { VMCNT(0); }
      __builtin_amdgcn_s_barrier();
      __builtin_amdgcn_sched_barrier(0);
    }
    ++cb; if (cb == 3) cb = 0;
  }

  // epilogue: C/D layout col=lane&15, row=quad*4+reg
#pragma unroll
  for (int mf = 0; mf < 4; ++mf) {
#pragma unroll
    for (int nf = 0; nf < 4; ++nf) {
      int n = n0 + wn + nf * 16 + lm;
      float bv = bias[n];
      int mrow = m0 + wm + mf * 16 + lq * 4;
      size_t rowbase = ((size_t)b * S_ + mrow) * H_ + n;
#pragma unroll
      for (int r = 0; r < 4; ++r) {
        float v = acc[mf][nf][r] + bv;
        if (OMODE == 0) {
          if (mat == 2) {
            // V: write directly in Vt chunk layout [b*NH+h][s>>3][dh][s&7]
            int s = mrow + r;
            ((bf16*)outp)[((size_t)(b * NH_ + (n >> 6))) * 32768 +
                          (size_t)(s >> 3) * 512 + (n & 63) * 8 + (s & 7)] =
                __float2bfloat16(v);
          } else {
            ((bf16*)outp)[rowbase + (size_t)r * H_] = __float2bfloat16(v);
          }
        } else {
          ((float*)outp)[rowbase + (size_t)r * H_] = v;
        }
      }
    }
  }
}

// ---------- attention: barrier-free flash, fully in-register softmax ----------
// Block = 4 independent waves x 32 q-rows, one (b,h). Swapped-operand MFMAs:
//   S^T = mfma(K', Q)  with K rows permuted at load so that lane (lq,lm) ends up
//   holding S for q = mf*16+lm, k = {8lq..8lq+3}+4(nf&1)+32(nf>>1) -> the 16 P
//   values each lane needs are exactly its own PV B-frag elements (no LDS, no
//   cross-lane P movement; cvt_pk packs them in-register).
//   O^T = mfma(V^T, P^T): the Vt chunk layout already IS the V^T A-frag, and the
//   O^T accumulator's q-index is lane&15 == softmax state's q-index, so rescale
//   and 1/l need no transpose. Row-reduce = 15 lane-local ops + 2 shfl_xor.
__global__ __launch_bounds__(256, 3) void k_attn(
    const bf16* __restrict__ Q, const bf16* __restrict__ K,
    const bf16* __restrict__ Vt, const float* __restrict__ mask,
    bf16* __restrict__ Ctx) {
  int bh = blockIdx.x;
  int b = bh / NH_, h = bh - b * NH_;
  int t = threadIdx.x, lane = t & 63, w = t >> 6;
  int lm = lane & 15, lq = lane >> 4;
  int q0 = blockIdx.y * 128 + w * 32;                // this wave's 32 q-rows

  // Q B-frags (col=q=lm, k=kf*32+lq*8+e), one-shot from global
  short8 qf[2][2];
#pragma unroll
  for (int mf = 0; mf < 2; ++mf)
#pragma unroll
    for (int kf = 0; kf < 2; ++kf)
      qf[mf][kf] = *(const short8*)(Q + ((size_t)(b * S_ + q0 + mf * 16 + lm)) * H_ +
                                    h * DH_ + kf * 32 + lq * 8);

  // permuted K row for the A-frag: load row lm holds K row kr + koff[nf]
  int kr = ((lm >> 2) << 3) + (lm & 3);
  const int koff[4] = {0, 4, 32, 36};
  const bf16* kbase = K + ((size_t)(b * S_) + kr) * H_ + h * DH_ + lq * 8;
  const bf16* vtb = Vt + ((size_t)(b * NH_ + h)) * 32768;
  const float* mbase = mask + (size_t)b * S_ + lq * 8;

  floatx4 oacc[2][4] = {};                           // O^T: rows d=nf*16+4lq+r, col q=mf*16+lm
  float m_[2] = {-1e30f, -1e30f}, l_[2] = {0.f, 0.f};

  for (int kt = 0; kt < 8; ++kt) {
    // ---- S^T = K' Q : K A-frags straight from global (permuted rows) ----
    floatx4 sT[2][4] = {};
#pragma unroll
    for (int kf = 0; kf < 2; ++kf) {
      short8 kb4[4];
#pragma unroll
      for (int nf = 0; nf < 4; ++nf)
        kb4[nf] = *(const short8*)(kbase + (size_t)(kt * 64 + koff[nf]) * H_ + kf * 32);
#pragma unroll
      for (int mf = 0; mf < 2; ++mf)
#pragma unroll
        for (int nf = 0; nf < 4; ++nf)
          sT[mf][nf] = __builtin_amdgcn_mfma_f32_16x16x32_bf16(kb4[nf], qf[mf][kf], sT[mf][nf], 0, 0, 0);
    }
    // ---- V^T A-frags (issue early; latency hides under softmax VALU) ----
    short8 vf[2][4];
#pragma unroll
    for (int kf = 0; kf < 2; ++kf)
#pragma unroll
      for (int nf = 0; nf < 4; ++nf)
        vf[kf][nf] = *(const short8*)(vtb + (size_t)(kt * 8 + kf * 4 + lq) * 512 +
                                      (nf * 16 + lm) * 8);
    // ---- mask slots: k_rel = koff[nf] + 8*lq + r ----
    const floatx4* mp = (const floatx4*)(mbase + kt * 64);
    floatx4 mv[4] = {mp[0], mp[1], mp[8], mp[9]};

    // ---- lane-local online softmax (q = mf*16+lm; 16 k-slots per lane) ----
    short8 pf[2][2];
#pragma unroll
    for (int mf = 0; mf < 2; ++mf) {
      float p[4][4];
#pragma unroll
      for (int nf = 0; nf < 4; ++nf)
#pragma unroll
        for (int r = 0; r < 4; ++r)
          p[nf][r] = sT[mf][nf][r] * 0.125f + mv[nf][r];
      float t01 = fmaxf(fmaxf(fmaxf(p[0][0], p[0][1]), fmaxf(p[0][2], p[0][3])),
                        fmaxf(fmaxf(p[1][0], p[1][1]), fmaxf(p[1][2], p[1][3])));
      float t23 = fmaxf(fmaxf(fmaxf(p[2][0], p[2][1]), fmaxf(p[2][2], p[2][3])),
                        fmaxf(fmaxf(p[3][0], p[3][1]), fmaxf(p[3][2], p[3][3])));
      float tm = fmaxf(t01, t23);
      tm = fmaxf(tm, __shfl_xor(tm, 16));
      tm = fmaxf(tm, __shfl_xor(tm, 32));
      float mn = fmaxf(m_[mf], tm);
      float a = __expf(m_[mf] - mn);
      m_[mf] = mn;
      float ps = 0.f;
#pragma unroll
      for (int nf = 0; nf < 4; ++nf)
#pragma unroll
        for (int r = 0; r < 4; ++r) {
          p[nf][r] = __expf(p[nf][r] - mn);
          ps += p[nf][r];
        }
      ps += __shfl_xor(ps, 16);
      ps += __shfl_xor(ps, 32);
      l_[mf] = l_[mf] * a + ps;
#pragma unroll
      for (int nf = 0; nf < 4; ++nf) oacc[mf][nf] *= a;
      union { short8 s8; unsigned u[4]; } pku;
      pku.u[0] = pk2(p[0][0], p[0][1]); pku.u[1] = pk2(p[0][2], p[0][3]);
      pku.u[2] = pk2(p[1][0], p[1][1]); pku.u[3] = pk2(p[1][2], p[1][3]);
      pf[mf][0] = pku.s8;
      pku.u[0] = pk2(p[2][0], p[2][1]); pku.u[1] = pk2(p[2][2], p[2][3]);
      pku.u[2] = pk2(p[3][0], p[3][1]); pku.u[3] = pk2(p[3][2], p[3][3]);
      pf[mf][1] = pku.s8;
    }
    // ---- O^T += V^T P^T ----
#pragma unroll
    for (int kf = 0; kf < 2; ++kf)
#pragma unroll
      for (int mf = 0; mf < 2; ++mf)
#pragma unroll
        for (int nf = 0; nf < 4; ++nf)
          oacc[mf][nf] = __builtin_amdgcn_mfma_f32_16x16x32_bf16(vf[kf][nf], pf[mf][kf], oacc[mf][nf], 0, 0, 0);
  }
  // ---- epilogue: O^T rows d=nf*16+4lq+r, col q=mf*16+lm; 8B vector stores ----
#pragma unroll
  for (int mf = 0; mf < 2; ++mf) {
    float inv = 1.f / l_[mf];
    bf16* op = Ctx + ((size_t)(b * S_ + q0 + mf * 16 + lm)) * H_ + h * DH_ + lq * 4;
#pragma unroll
    for (int nf = 0; nf < 4; ++nf) {
      uint2v o;
      o.x = pk2(oacc[mf][nf][0] * inv, oacc[mf][nf][1] * inv);
      o.y = pk2(oacc[mf][nf][2] * inv, oacc[mf][nf][3] * inv);
      *(uint2v*)(op + nf * 16) = o;
    }
  }
}

extern "C" void kernel_launch(void* const* d_in, const int* in_sizes, int n_in,
                              void* d_out, int out_size, void* d_ws, size_t ws_size,
                              hipStream_t stream) {
  const float* X    = (const float*)d_in[0];
  const float* mask = (const float*)d_in[1];
  const float* Wq   = (const float*)d_in[2];
  const float* bq   = (const float*)d_in[3];
  const float* Wk   = (const float*)d_in[4];
  const float* bk   = (const float*)d_in[5];
  const float* Wv   = (const float*)d_in[6];
  const float* bv   = (const float*)d_in[7];
  const float* Wo   = (const float*)d_in[8];
  const float* bo   = (const float*)d_in[9];
  const float* Wsc  = (const float*)d_in[10];
  const float* bsc  = (const float*)d_in[11];
  const float* Wsu  = (const float*)d_in[12];
  const float* bsu  = (const float*)d_in[13];

  char* ws = (char*)d_ws;
  int*   eidx    = (int*)ws;                        //       128 B @ 0
  float* logits  = (float*)(ws + 128);              //     1,024 B
  float* partial = (float*)(ws + 1280);             //   786,432 B
  float* hmean   = (float*)(ws + 787712);           //    98,304 B
  bf16*  Xh      = (bf16*)(ws + 886016);            // 25,165,824 B
  bf16*  Wt      = (bf16*)(ws + 26051840);          // 37,748,736 B
  bf16*  qb      = (bf16*)(ws + 63800576);          // 25,165,824 B
  bf16*  kb      = (bf16*)(ws + 88966400);          // 25,165,824 B
  bf16*  Vt      = (bf16*)(ws + 114132224);         // 25,165,824 B -> 139,298,048 total
  bf16*  ctx     = Xh;                              // alias: Xh dead after QKV GEMM

  k_mean_convert<<<dim3(96, 8), 256, 0, stream>>>(X, Xh, partial);
  k_mean_reduce<<<96, 256, 0, stream>>>(partial, hmean);
  k_wt<<<dim3(24, 24, 32), 256, 0, stream>>>(Wq, Wk, Wv, Wo, Wt);
  k_gate<<<B_, 64, 0, stream>>>(hmean, Wsc, bsc, Wsu, bsu, logits);
  k_route2<<<1, 64, 0, stream>>>(logits, eidx);
  // QKV: 32 b x 3 mats x 24 tiles = 2304 blocks = 9 x 256 CUs (exact balance)
  k_gemm<0, 3><<<dim3(2304), 256, 0, stream>>>(Xh, Wt, bq, bk, bv,
                                               (void*)qb, (void*)kb, (void*)Vt, eidx, 0);
  k_attn<<<dim3(B_ * NH_, 4), 256, 0, stream>>>(qb, kb, Vt, mask, ctx);
  // O: 32 b x 24 tiles = 768 blocks = 3 x 256 CUs (exact balance)
  k_gemm<1, 1><<<dim3(768), 256, 0, stream>>>(ctx, Wt, bo, bo, bo,
                                              d_out, d_out, d_out, eidx, 3);
}